// Round 5
// baseline (270.174 us; speedup 1.0000x reference)
//
#include <hip/hip_runtime.h>

#define SEG 256
#define SMOOTH_K 9
#define BASE_AMP 0.08f
#define L 4096
#define ROW (2 * L)            // floats per batch row (8192)
#define ROW4 (ROW / 4)         // float4 per row (2048)

// ws layout (floats):
//   [0   .. 257]  pat0 zero-padded: [0]=0, [1..256]=pat_i, [257]=0
//   [258 .. 515]  pat1 zero-padded
//   [768 .. 768+B-1] ssq[b]
#define WS_SSQ 768

// ---------------------------------------------------------------------------
// K1: effective pattern -> padded tables; also zero ssq[].
// ---------------------------------------------------------------------------
__global__ __launch_bounds__(256) void pattern_kernel(
    const float* __restrict__ pi, const float* __restrict__ pq,
    float* __restrict__ ws, int B) {
    __shared__ float wsum0[4], wsum1[4], wsq[4];

    const int i = threadIdx.x;            // 0..255 (position)

    // zero the ssq accumulators (ws is poisoned 0xAA before every call)
    for (int k = i; k < B; k += 256) ws[WS_SSQ + k] = 0.f;

    // 'same' box smooth, zero padding, always /9 (count_include_pad=True)
    float v0 = 0.f, v1 = 0.f;
    #pragma unroll
    for (int j = -(SMOOTH_K / 2); j <= SMOOTH_K / 2; ++j) {
        int k = i + j;
        if (k >= 0 && k < SEG) { v0 += pi[k]; v1 += pq[k]; }
    }
    v0 *= (1.0f / SMOOTH_K);
    v1 *= (1.0f / SMOOTH_K);

    float s0 = v0, s1 = v1;
    #pragma unroll
    for (int off = 32; off; off >>= 1) {
        s0 += __shfl_down(s0, off);
        s1 += __shfl_down(s1, off);
    }
    const int wid = i >> 6, lane = i & 63;
    if (lane == 0) { wsum0[wid] = s0; wsum1[wid] = s1; }
    __syncthreads();
    const float m0 = (wsum0[0] + wsum0[1] + wsum0[2] + wsum0[3]) * (1.0f / SEG);
    const float m1 = (wsum1[0] + wsum1[1] + wsum1[2] + wsum1[3]) * (1.0f / SEG);
    const float d0 = v0 - m0;
    const float d1 = v1 - m1;

    float q = d0 * d0 + d1 * d1;
    #pragma unroll
    for (int off = 32; off; off >>= 1) q += __shfl_down(q, off);
    if (lane == 0) wsq[wid] = q;
    __syncthreads();
    const float msq = (wsq[0] + wsq[1] + wsq[2] + wsq[3]) * (1.0f / (2 * SEG));
    const float scale = BASE_AMP / sqrtf(msq + 1e-8f);

    ws[1 + i]       = d0 * scale;         // padded channel 0
    ws[258 + 1 + i] = d1 * scale;         // padded channel 1
    if (i == 0) { ws[0] = 0.f; ws[257] = 0.f; ws[258] = 0.f; ws[515] = 0.f; }
}

// ---------------------------------------------------------------------------
// K2: flat fill-shaped stream: out = x (pure copy), per-wave ssq reduction
// off the store path (shuffle tree + 1 atomicAdd per wave-iteration).
// No LDS, no barriers. 2048 blocks -> 32 waves/CU.
// ---------------------------------------------------------------------------
__global__ __launch_bounds__(256) void copy_reduce_kernel(
    const float4* __restrict__ x4, float4* __restrict__ out4,
    float* __restrict__ ssq, int n4) {
    int i = blockIdx.x * 256 + threadIdx.x;
    const int stride = gridDim.x * 256;
    for (; i < n4; i += stride) {
        const float4 v = x4[i];
        out4[i] = v;                              // store: no dependencies
        float q = v.x * v.x + v.y * v.y + v.z * v.z + v.w * v.w;
        #pragma unroll
        for (int off = 32; off; off >>= 1) q += __shfl_down(q, off);
        // one wave covers 64 consecutive float4 -> same row (64 | 2048)
        if ((threadIdx.x & 63) == 0) atomicAdd(&ssq[i >> 11], q);
    }
}

// ---------------------------------------------------------------------------
// K3: patch the segment only. One small block per row; x re-read is L3-hot
// (~17 MB total). amp finished from ssq; zero-padded pattern in L2.
// ---------------------------------------------------------------------------
__global__ __launch_bounds__(192) void patch_kernel(
    const float* __restrict__ x, const int* __restrict__ starts,
    const float* __restrict__ ws, float* __restrict__ out) {
    const int b = blockIdx.x;
    const int t = threadIdx.x;

    const int s    = starts[b];
    const int s4   = s >> 2;                 // first overlapping float4 (per ch)
    const int e4   = (s + SEG - 1) >> 2;     // last overlapping float4 (per ch)
    const int nper = e4 - s4 + 1;            // 64 or 65
    if (t >= 2 * nper) return;

    const float amp = sqrtf(ws[WS_SSQ + b] * (1.0f / ROW) + 1e-12f);

    const int c  = (t >= nper) ? 1 : 0;
    const int j  = t - c * nper;
    const int l4 = s4 + j;
    const int idx = (c << 10) + l4;          // float4 index within row

    const float4* __restrict__ xr =
        reinterpret_cast<const float4*>(x + (size_t)b * ROW);
    float4* __restrict__ outr = reinterpret_cast<float4*>(out + (size_t)b * ROW);

    float4 v = xr[idx];
    const float* __restrict__ pc = ws + c * 258;   // zero-padded table
    const int r = (l4 << 2) - s;                   // in [-3, 255]
    v.x += amp * pc[1 + min(max(r,     -1), SEG)];
    v.y += amp * pc[1 + min(max(r + 1, -1), SEG)];
    v.z += amp * pc[1 + min(max(r + 2, -1), SEG)];
    v.w += amp * pc[1 + min(max(r + 3, -1), SEG)];
    outr[idx] = v;
}

// ---------------------------------------------------------------------------
extern "C" void kernel_launch(void* const* d_in, const int* in_sizes, int n_in,
                              void* d_out, int out_size, void* d_ws,
                              size_t ws_size, hipStream_t stream) {
    const float* x      = (const float*)d_in[0];
    const float* pi     = (const float*)d_in[1];
    const float* pq     = (const float*)d_in[2];
    const int*   starts = (const int*)d_in[3];
    float* out = (float*)d_out;
    float* ws  = (float*)d_ws;

    const int B  = in_sizes[0] / ROW;        // 4096
    const int n4 = B * ROW4;                 // total float4

    pattern_kernel<<<1, 256, 0, stream>>>(pi, pq, ws, B);
    copy_reduce_kernel<<<2048, 256, 0, stream>>>(
        reinterpret_cast<const float4*>(x), reinterpret_cast<float4*>(out),
        ws + WS_SSQ, n4);
    patch_kernel<<<B, 192, 0, stream>>>(x, starts, ws, out);
}

// Round 7
// 229.397 us; speedup vs baseline: 1.1778x; 1.1778x over previous
//
#include <hip/hip_runtime.h>

#define SEG 256
#define SMOOTH_K 9
#define BASE_AMP 0.08f
#define L 4096
#define ROW (2 * L)          // floats per batch row (8192)

typedef float vfloat4 __attribute__((ext_vector_type(4)));  // nt-builtin-compatible

// ---------------------------------------------------------------------------
// K1: effective pattern -> d_ws (512 floats: [2][256])
// ---------------------------------------------------------------------------
__global__ __launch_bounds__(256) void pattern_kernel(
    const float* __restrict__ pi, const float* __restrict__ pq,
    float* __restrict__ pat_out) {
    __shared__ float wsum0[4], wsum1[4], wsq[4];

    const int i = threadIdx.x;            // 0..255 (position)
    // 'same' box smooth, zero padding, always /9 (count_include_pad=True)
    float v0 = 0.f, v1 = 0.f;
    #pragma unroll
    for (int j = -(SMOOTH_K / 2); j <= SMOOTH_K / 2; ++j) {
        int k = i + j;
        if (k >= 0 && k < SEG) { v0 += pi[k]; v1 += pq[k]; }
    }
    v0 *= (1.0f / SMOOTH_K);
    v1 *= (1.0f / SMOOTH_K);

    float s0 = v0, s1 = v1;
    #pragma unroll
    for (int off = 32; off; off >>= 1) {
        s0 += __shfl_down(s0, off);
        s1 += __shfl_down(s1, off);
    }
    const int wid = i >> 6, lane = i & 63;
    if (lane == 0) { wsum0[wid] = s0; wsum1[wid] = s1; }
    __syncthreads();
    const float m0 = (wsum0[0] + wsum0[1] + wsum0[2] + wsum0[3]) * (1.0f / SEG);
    const float m1 = (wsum1[0] + wsum1[1] + wsum1[2] + wsum1[3]) * (1.0f / SEG);
    const float d0 = v0 - m0;
    const float d1 = v1 - m1;

    float q = d0 * d0 + d1 * d1;
    #pragma unroll
    for (int off = 32; off; off >>= 1) q += __shfl_down(q, off);
    if (lane == 0) wsq[wid] = q;
    __syncthreads();
    const float msq = (wsq[0] + wsq[1] + wsq[2] + wsq[3]) * (1.0f / (2 * SEG));
    const float scale = BASE_AMP / sqrtf(msq + 1e-8f);

    pat_out[i]       = d0 * scale;
    pat_out[SEG + i] = d1 * scale;
}

// ---------------------------------------------------------------------------
// K2: fused single pass, one block per row. Non-temporal loads/stores keep
// the out-stream from allocating in L3, so x stays L3-resident for reads.
// Non-segment float4s are stored immediately (no dependency on reduction);
// segment float4s stashed in LDS, patched after the block reduce.
// ---------------------------------------------------------------------------
__global__ __launch_bounds__(256) void apply_kernel(
    const float* __restrict__ x, const int* __restrict__ starts,
    const float* __restrict__ pat, float* __restrict__ out) {
    const int b = blockIdx.x;
    const int t = threadIdx.x;

    const vfloat4* __restrict__ xr =
        reinterpret_cast<const vfloat4*>(x + (size_t)b * ROW);
    vfloat4* __restrict__ outr =
        reinterpret_cast<vfloat4*>(out + (size_t)b * ROW);

    __shared__ float   spat[2 * SEG];
    __shared__ vfloat4 stash[2 * 66];  // per-channel contiguous slice, <=65 each
    __shared__ float   wred[4];

    spat[t]       = pat[t];
    spat[t + SEG] = pat[t + SEG];

    const int s    = starts[b];
    const int s4   = s >> 2;                 // first overlapping float4 (per ch)
    const int e4   = (s + SEG - 1) >> 2;     // last overlapping float4 (per ch)
    const int nper = e4 - s4 + 1;            // 64 or 65

    float ssq = 0.f;
    #pragma unroll
    for (int k = 0; k < 8; ++k) {
        const int idx = t + k * 256;         // float4 index within row
        vfloat4 v = __builtin_nontemporal_load(&xr[idx]);
        ssq += v.x * v.x + v.y * v.y + v.z * v.z + v.w * v.w;
        const int c  = idx >> 10;            // channel
        const int l4 = idx & 1023;           // float4 index within channel
        if (l4 >= s4 && l4 <= e4) {
            stash[c * 66 + (l4 - s4)] = v;   // defer until amp is known
        } else {
            __builtin_nontemporal_store(v, &outr[idx]);  // streams, no L3 alloc
        }
    }

    // block reduce sum-of-squares
    #pragma unroll
    for (int off = 32; off; off >>= 1) ssq += __shfl_down(ssq, off);
    if ((t & 63) == 0) wred[t >> 6] = ssq;
    __syncthreads();   // covers stash, spat, wred
    const float amp =
        sqrtf((wred[0] + wred[1] + wred[2] + wred[3]) * (1.0f / ROW) + 1e-12f);

    // tail: patch the stashed float4s (2*nper <= 130 threads active)
    if (t < 2 * nper) {
        const int c  = (t >= nper) ? 1 : 0;
        const int j  = t - c * nper;
        const int l4 = s4 + j;
        vfloat4 v = stash[c * 66 + j];
        const float* __restrict__ pc = spat + c * SEG;
        const int r = (l4 << 2) - s;         // in [-3, 255]
        if (r >= 0     && r < SEG)     v.x += amp * pc[r];
        if (r + 1 >= 0 && r + 1 < SEG) v.y += amp * pc[r + 1];
        if (r + 2 >= 0 && r + 2 < SEG) v.z += amp * pc[r + 2];
        if (r + 3 >= 0 && r + 3 < SEG) v.w += amp * pc[r + 3];
        __builtin_nontemporal_store(v, &outr[(c << 10) + l4]);
    }
}

// ---------------------------------------------------------------------------
extern "C" void kernel_launch(void* const* d_in, const int* in_sizes, int n_in,
                              void* d_out, int out_size, void* d_ws,
                              size_t ws_size, hipStream_t stream) {
    const float* x      = (const float*)d_in[0];
    const float* pi     = (const float*)d_in[1];
    const float* pq     = (const float*)d_in[2];
    const int*   starts = (const int*)d_in[3];
    float* out = (float*)d_out;
    float* pat = (float*)d_ws;   // 512 floats

    const int B = in_sizes[0] / ROW;   // 4096

    pattern_kernel<<<1, 256, 0, stream>>>(pi, pq, pat);
    apply_kernel<<<B, 256, 0, stream>>>(x, starts, pat, out);
}